// Round 1
// baseline (413.001 us; speedup 1.0000x reference)
//
#include <hip/hip_runtime.h>
#include <math.h>

#define BATCH 2048
#define NN 64
#define FEAT 40
#define M 10
#define WAVES 10
#define BLOCK (WAVES * 64)
#define PDS 65  // padded row stride for pd matrix (2-way bank alias only -> free)

// broadcast value from lane `l` (compile-time const) to all lanes as uniform
__device__ __forceinline__ float bl(float v, int l) {
    return __int_as_float(__builtin_amdgcn_readlane(__float_as_int(v), l));
}

// full 64-lane butterfly sum
__device__ __forceinline__ float wsum(float v) {
#pragma unroll
    for (int o = 32; o >= 1; o >>= 1) v += __shfl_xor(v, o, 64);
    return v;
}

__global__ __launch_bounds__(BLOCK) void muygps_kernel(
    const float* __restrict__ x,      // (20000, 40)
    const float* __restrict__ ls,     // (10,)
    const float* __restrict__ epsv,   // (10,)
    const int*   __restrict__ bidx,   // (2048,)
    const int*   __restrict__ nidx,   // (2048, 64)
    const float* __restrict__ tgt,    // (2048, 64, 10)
    float* __restrict__ out)          // pred(2048,10) | var(2048,10) | sigma(10)
{
    __shared__ float xnT[FEAT][NN];   // transposed neighbor features
    __shared__ float xbs[FEAT];       // batch-point features
    __shared__ float pds[NN * PDS];   // pairwise l2 distances (already sqrt'ed)
    __shared__ float cds[NN];         // crosswise l2 distances

    const int b    = blockIdx.x;
    const int t    = threadIdx.x;
    const int w    = t >> 6;          // wave id 0..9
    const int lane = t & 63;

    // ---- phase 1: gather x rows into LDS (transposed) ----
    if (t < FEAT) xbs[t] = x[(long)bidx[b] * FEAT + t];
    for (int flat = t; flat < NN * FEAT; flat += BLOCK) {
        int n = flat & 63;       // consecutive threads -> consecutive n: conflict-free LDS writes
        int f = flat >> 6;
        xnT[f][n] = x[(long)nidx[b * NN + n] * FEAT + f];
    }
    __syncthreads();

    // ---- phase 2: distance matrix rows (64 pd rows + 1 cd row), striped over waves ----
    for (int r = w; r < NN + 1; r += WAVES) {
        float d2 = 0.f;
        if (r < NN) {
#pragma unroll
            for (int f = 0; f < FEAT; ++f) {
                float diff = xnT[f][r] - xnT[f][lane];
                d2 = fmaf(diff, diff, d2);
            }
            pds[r * PDS + lane] = sqrtf(d2);   // r==lane gives exactly 0
        } else {
#pragma unroll
            for (int f = 0; f < FEAT; ++f) {
                float diff = xbs[f] - xnT[f][lane];
                d2 = fmaf(diff, diff, d2);
            }
            cds[lane] = sqrtf(d2);
        }
    }
    __syncthreads();

    // ---- phase 3: wave w == model m; row-per-lane in-register Cholesky ----
    const int m = w;
    const float il = -1.0f / ls[m];
    const float ep = epsv[m];

    float A[NN];  // row `lane` of Kp
    {
        const float* prow = &pds[lane * PDS];
#pragma unroll
        for (int j = 0; j < NN; ++j) {
            float v = __expf(prow[j] * il);
            A[j] = (j == lane) ? (v + ep) : v;
        }
    }

    // right-looking Cholesky; after step k, register k of lane i (i>=k) holds L[i][k]
    float invd = 0.f;  // lane k keeps 1/L[k][k]
#pragma unroll
    for (int k = 0; k < NN; ++k) {
        float akk = bl(A[k], k);
        float id  = rsqrtf(akk);
        A[k] *= id;                      // column k of L (distributed over lanes)
        if (lane == k) invd = id;
#pragma unroll
        for (int j = k + 1; j < NN; ++j) {
            float cj = bl(A[k], j);      // L[j][k]
            A[j] = fmaf(-A[k], cj, A[j]); // A[i][j] -= L[i][k]*L[j][k]
        }
    }

    // ---- two forward solves: w1 = L^-1 Y_m, w2 = L^-1 Kcross_m ----
    float Kc = __expf(cds[lane] * il);
    float yv = tgt[(b * NN + lane) * M + m];

    float b1 = yv, b2 = Kc;
    float w1 = 0.f, w2 = 0.f;
#pragma unroll
    for (int k = 0; k < NN; ++k) {
        float ik = bl(invd, k);
        float t1 = bl(b1, k) * ik;
        float t2 = bl(b2, k) * ik;
        if (lane == k) { w1 = t1; w2 = t2; }
        b1 = fmaf(-A[k], t1, b1);
        b2 = fmaf(-A[k], t2, b2);
    }

    // ---- outputs: quadratic forms, no backward solves needed ----
    float pred = wsum(w1 * w2);          // Kc^T Kp^-1 Y
    float quad = wsum(w2 * w2);          // Kc^T Kp^-1 Kc
    float sig  = wsum(w1 * w1);          // Y^T Kp^-1 Y
    if (lane == 0) {
        out[b * M + m] = pred;
        out[BATCH * M + b * M + m] = 1.0f - quad;
        atomicAdd(&out[2 * BATCH * M + m], sig * (1.0f / (float)(BATCH * NN)));
    }
}

extern "C" void kernel_launch(void* const* d_in, const int* in_sizes, int n_in,
                              void* d_out, int out_size, void* d_ws, size_t ws_size,
                              hipStream_t stream) {
    const float* x   = (const float*)d_in[0];
    const float* ls  = (const float*)d_in[1];
    const float* ep  = (const float*)d_in[2];
    const int*   bi  = (const int*)d_in[3];
    const int*   ni  = (const int*)d_in[4];
    const float* tg  = (const float*)d_in[5];
    float* out = (float*)d_out;

    // sigma_sq region is accumulated via atomics; d_out is poisoned each launch
    hipMemsetAsync(out + 2 * BATCH * M, 0, M * sizeof(float), stream);
    muygps_kernel<<<BATCH, BLOCK, 0, stream>>>(x, ls, ep, bi, ni, tg, out);
}

// Round 2
// 407.447 us; speedup vs baseline: 1.0136x; 1.0136x over previous
//
#include <hip/hip_runtime.h>
#include <math.h>

#define BATCH 2048
#define NN 64
#define FEAT 40
#define M 10
#define WAVES 10
#define BLOCK (WAVES * 64)
#define PDS 65  // padded row stride for pd matrix (2-way bank alias only -> free)

// broadcast value from lane `l` (compile-time const after unroll) to all lanes
__device__ __forceinline__ float bl(float v, int l) {
    return __int_as_float(__builtin_amdgcn_readlane(__float_as_int(v), l));
}

// full 64-lane butterfly sum
__device__ __forceinline__ float wsum(float v) {
#pragma unroll
    for (int o = 32; o >= 1; o >>= 1) v += __shfl_xor(v, o, 64);
    return v;
}

// launch_bounds(640, 5): min 5 waves/SIMD -> VGPR cap ~102. Without this the
// compiler capped at 40 arch VGPRs and shuttled A[64] through AGPRs
// (v_accvgpr_read/write around every Cholesky access) -> ~3x VALU inflation.
// Occupancy is LDS-limited (27.6KB/block) anyway, so high VGPR count is free.
__global__ __launch_bounds__(BLOCK, 5) void muygps_kernel(
    const float* __restrict__ x,      // (20000, 40)
    const float* __restrict__ ls,     // (10,)
    const float* __restrict__ epsv,   // (10,)
    const int*   __restrict__ bidx,   // (2048,)
    const int*   __restrict__ nidx,   // (2048, 64)
    const float* __restrict__ tgt,    // (2048, 64, 10)
    float* __restrict__ out)          // pred(2048,10) | var(2048,10) | sigma(10)
{
    __shared__ float xnT[FEAT][NN];   // transposed neighbor features
    __shared__ float xbs[FEAT];       // batch-point features
    __shared__ float pds[NN * PDS];   // pairwise l2 distances (sqrt'ed)
    __shared__ float cds[NN];         // crosswise l2 distances

    const int b    = blockIdx.x;
    const int t    = threadIdx.x;
    const int w    = t >> 6;          // wave id 0..9
    const int lane = t & 63;

    // ---- phase 1: gather x rows into LDS (transposed) ----
    if (t < FEAT) xbs[t] = x[(long)bidx[b] * FEAT + t];
    for (int flat = t; flat < NN * FEAT; flat += BLOCK) {
        int n = flat & 63;       // consecutive threads -> consecutive n: conflict-free
        int f = flat >> 6;
        xnT[f][n] = x[(long)nidx[b * NN + n] * FEAT + f];
    }
    __syncthreads();

    // ---- phase 2: distance rows (64 pd rows + 1 cd row), striped over waves ----
    for (int r = w; r < NN + 1; r += WAVES) {
        float d2 = 0.f;
        if (r < NN) {
#pragma unroll
            for (int f = 0; f < FEAT; ++f) {
                float diff = xnT[f][r] - xnT[f][lane];
                d2 = fmaf(diff, diff, d2);
            }
            pds[r * PDS + lane] = sqrtf(d2);   // r==lane gives exactly 0
        } else {
#pragma unroll
            for (int f = 0; f < FEAT; ++f) {
                float diff = xbs[f] - xnT[f][lane];
                d2 = fmaf(diff, diff, d2);
            }
            cds[lane] = sqrtf(d2);
        }
    }
    __syncthreads();

    // ---- phase 3: wave w == model m; row-per-lane in-register Cholesky ----
    const int m = w;
    const float il = -1.0f / ls[m];
    const float ep = epsv[m];

    float A[NN];  // row `lane` of Kp, kept in arch VGPRs
    {
        const float* prow = &pds[lane * PDS];
#pragma unroll
        for (int j = 0; j < NN; ++j) {
            float v = __expf(prow[j] * il);
            A[j] = (j == lane) ? (v + ep) : v;
        }
    }

    // right-looking Cholesky; after step k, register k of lane i (i>=k) holds L[i][k]
    float invd = 0.f;  // lane k keeps 1/L[k][k]
#pragma unroll
    for (int k = 0; k < NN; ++k) {
        float akk = bl(A[k], k);
        float id  = rsqrtf(akk);
        A[k] *= id;                       // column k of L (distributed over lanes)
        if (lane == k) invd = id;
#pragma unroll
        for (int j = k + 1; j < NN; ++j) {
            float cj = bl(A[k], j);       // L[j][k]
            A[j] = fmaf(-A[k], cj, A[j]); // A[i][j] -= L[i][k]*L[j][k]
        }
    }

    // ---- two forward solves: w1 = L^-1 Y_m, w2 = L^-1 Kcross_m ----
    float Kc = __expf(cds[lane] * il);
    float yv = tgt[(b * NN + lane) * M + m];

    float b1 = yv, b2 = Kc;
    float w1 = 0.f, w2 = 0.f;
#pragma unroll
    for (int k = 0; k < NN; ++k) {
        float ik = bl(invd, k);
        float t1 = bl(b1, k) * ik;
        float t2 = bl(b2, k) * ik;
        if (lane == k) { w1 = t1; w2 = t2; }
        b1 = fmaf(-A[k], t1, b1);
        b2 = fmaf(-A[k], t2, b2);
    }

    // ---- outputs: quadratic forms, no backward solves needed ----
    float pred = wsum(w1 * w2);          // Kc^T Kp^-1 Y
    float quad = wsum(w2 * w2);          // Kc^T Kp^-1 Kc
    float sig  = wsum(w1 * w1);          // Y^T Kp^-1 Y
    if (lane == 0) {
        out[b * M + m] = pred;
        out[BATCH * M + b * M + m] = 1.0f - quad;
        atomicAdd(&out[2 * BATCH * M + m], sig * (1.0f / (float)(BATCH * NN)));
    }
}

extern "C" void kernel_launch(void* const* d_in, const int* in_sizes, int n_in,
                              void* d_out, int out_size, void* d_ws, size_t ws_size,
                              hipStream_t stream) {
    const float* x   = (const float*)d_in[0];
    const float* ls  = (const float*)d_in[1];
    const float* ep  = (const float*)d_in[2];
    const int*   bi  = (const int*)d_in[3];
    const int*   ni  = (const int*)d_in[4];
    const float* tg  = (const float*)d_in[5];
    float* out = (float*)d_out;

    // sigma_sq region is accumulated via atomics; d_out is poisoned each launch
    hipMemsetAsync(out + 2 * BATCH * M, 0, M * sizeof(float), stream);
    muygps_kernel<<<BATCH, BLOCK, 0, stream>>>(x, ls, ep, bi, ni, tg, out);
}